// Round 7
// baseline (2728.538 us; speedup 1.0000x reference)
//
#include <hip/hip_runtime.h>

// CV quantum neural network simulator, D=8 cutoff, M=4 modes, L=4 layers.
// R11: raise cmac-per-LDS-read ratio. R10 showed: VALU 44%, LDS pipe ~38%,
// no saturated pipe, traffic nil -> cut total ds-op count. BS gate
// re-partitioned by (sample, row-group): wave wq = sample wq>>1, output rows
// 4(wq&1)..+3, 32 named accumulators (2x Acc16 = 64 VGPR). Each LDS read now
// feeds up to 4 outputs: 54 reads / 172 cmacs per thread (was 144/172).
// Sample offset folds additively into pb (bit 12, disjoint from XOR bits) ->
// only 2 BS instantiations per mode pair. cmac reverted to scalar FMA (R10's
// pk_fma marshalling ate its gain). Numerics bit-identical (same per-output
// ka-ascending accumulation order).

#define NM 4
#define NL 4
#define AMPS 4096

__device__ __forceinline__ void cmac(float2& acc, float2 a, float2 b) {
    acc.x = fmaf(a.x, b.x, acc.x);
    acc.x = fmaf(-a.y, b.y, acc.x);
    acc.y = fmaf(a.x, b.y, acc.y);
    acc.y = fmaf(a.y, b.x, acc.y);
}
__device__ __forceinline__ float2 cmul(float2 a, float2 b) {
    return make_float2(a.x * b.x - a.y * b.y, a.x * b.y + a.y * b.x);
}

// F2-linear physical-slot map (bank-conflict-free for all access patterns).
__host__ __device__ constexpr int physw(int e) {
    int l0 = ((e >> 0) ^ (e >> 5) ^ (e >> 7) ^ (e >> 9)) & 1;
    int l1 = ((e >> 1) ^ (e >> 3) ^ (e >> 8) ^ (e >> 10)) & 1;
    int l2 = ((e >> 2) ^ (e >> 4) ^ (e >> 6) ^ (e >> 11)) & 1;
    int l3 = ((e >> 3) ^ (e >> 6) ^ (e >> 9)) & 1;
    return (e & ~15) | l0 | (l1 << 1) | (l2 << 2) | (l3 << 3);
}

// 16 named float2 accumulators -- cannot be demoted to scratch.
struct Acc16 {
    float2 v0,v1,v2,v3,v4,v5,v6,v7,v8,v9,v10,v11,v12,v13,v14,v15;
    template<int I> __device__ __forceinline__ float2& get() {
        if constexpr (I == 0) return v0;  else if constexpr (I == 1) return v1;
        else if constexpr (I == 2) return v2;  else if constexpr (I == 3) return v3;
        else if constexpr (I == 4) return v4;  else if constexpr (I == 5) return v5;
        else if constexpr (I == 6) return v6;  else if constexpr (I == 7) return v7;
        else if constexpr (I == 8) return v8;  else if constexpr (I == 9) return v9;
        else if constexpr (I == 10) return v10; else if constexpr (I == 11) return v11;
        else if constexpr (I == 12) return v12; else if constexpr (I == 13) return v13;
        else if constexpr (I == 14) return v14; else return v15;
    }
    __device__ __forceinline__ void zero() {
        float2 z = make_float2(0.f, 0.f);
        v0=z; v1=z; v2=z; v3=z; v4=z; v5=z; v6=z; v7=z;
        v8=z; v9=z; v10=z; v11=z; v12=z; v13=z; v14=z; v15=z;
    }
};

// ---------------------------------------------------------------------------
// Kernel 1: coherent vectors = first column of expm(x*(AD - A)).
// ---------------------------------------------------------------------------
__global__ void coh_kernel(const float* __restrict__ x, float* __restrict__ coh, int total) {
    int t = blockIdx.x * blockDim.x + threadIdx.x;
    if (t >= total) return;
    float alpha = x[t];
    const float sq1 = 1.0f, sq2 = 1.41421356f, sq3 = 1.73205081f, sq4 = 2.0f,
                sq5 = 2.23606798f, sq6 = 2.44948975f, sq7 = 2.64575131f;
    float v0 = 1.f, v1 = 0.f, v2 = 0.f, v3 = 0.f, v4 = 0.f, v5 = 0.f, v6 = 0.f, v7 = 0.f;
    const int NS = 32;
    float h = alpha / (float)NS;
    for (int s = 0; s < NS; s++) {
        float w0 = v0, w1 = v1, w2 = v2, w3 = v3, w4 = v4, w5 = v5, w6 = v6, w7 = v7;
        float t0 = v0, t1 = v1, t2 = v2, t3 = v3, t4 = v4, t5 = v5, t6 = v6, t7 = v7;
        #pragma unroll
        for (int j = 1; j <= 8; j++) {
            float c = h / (float)j;
            float n0 = c * (          - sq1 * t1);
            float n1 = c * (sq1 * t0 - sq2 * t2);
            float n2 = c * (sq2 * t1 - sq3 * t3);
            float n3 = c * (sq3 * t2 - sq4 * t4);
            float n4 = c * (sq4 * t3 - sq5 * t5);
            float n5 = c * (sq5 * t4 - sq6 * t6);
            float n6 = c * (sq6 * t5 - sq7 * t7);
            float n7 = c * (sq7 * t6            );
            t0 = n0; t1 = n1; t2 = n2; t3 = n3; t4 = n4; t5 = n5; t6 = n6; t7 = n7;
            w0 += t0; w1 += t1; w2 += t2; w3 += t3; w4 += t4; w5 += t5; w6 += t6; w7 += t7;
        }
        v0 = w0; v1 = w1; v2 = w2; v3 = w3; v4 = w4; v5 = w5; v6 = w6; v7 = w7;
    }
    float* dst = coh + t * 8;
    dst[0] = v0; dst[1] = v1; dst[2] = v2; dst[3] = v3;
    dst[4] = v4; dst[5] = v5; dst[6] = v6; dst[7] = v7;
}

// ---------------------------------------------------------------------------
// Kernel 2: 8x8 complex expm. Blocks 0..15: squeeze. Blocks 16..31:
// displacement with Kerr folded (row scale). Stored transposed [k*8+i].
// ---------------------------------------------------------------------------
__global__ __launch_bounds__(64) void expm8_kernel(
    const float* __restrict__ sqr, const float* __restrict__ sqph,
    const float* __restrict__ dpr, const float* __restrict__ dpph,
    const float* __restrict__ kerr,
    float2* __restrict__ sqm, float2* __restrict__ dpm) {
    __shared__ float2 X[64], R[64];
    int t = threadIdx.x;
    int r = t >> 3, c = t & 7;
    int bid = blockIdx.x;
    float2 h = make_float2(0.f, 0.f);
    float normb;
    if (bid < 16) {
        float rr = sqr[bid], ph = sqph[bid];
        float zr = rr * cosf(ph), zi = rr * sinf(ph);
        if (c == r + 2) { float f = 0.5f * sqrtf((float)((r + 1) * (r + 2))); h.x =  f * zr; h.y = -f * zi; }
        if (r == c + 2) { float f = 0.5f * sqrtf((float)((c + 1) * (c + 2))); h.x = -f * zr; h.y = -f * zi; }
        normb = fabsf(rr) * 5.5f;
    } else {
        int g = bid - 16;
        float rr = dpr[g], ph = dpph[g];
        float am = rr * cosf(ph);
        float aph = rr * sinf(ph);
        float ar = am * cosf(aph), ai = am * sinf(aph);
        if (r == c + 1) { float f = sqrtf((float)r); h.x += ar * f; h.y += ai * f; }
        if (c == r + 1) { float f = sqrtf((float)c); h.x -= ar * f; h.y += ai * f; }
        normb = fabsf(am) * 5.5f;
    }
    int s = 0;
    while (normb > 0.2f && s < 20) { normb *= 0.5f; s++; }
    float fs = 1.f;
    for (int q = 0; q < s; q++) fs *= 0.5f;
    float2 xs = make_float2(h.x * fs, h.y * fs);
    X[t] = xs;
    float idel = (r == c) ? 1.f : 0.f;
    R[t] = make_float2(idel + xs.x / 9.f, xs.y / 9.f);
    __syncthreads();
    for (int j = 8; j >= 1; j--) {
        float2 acc = make_float2(0.f, 0.f);
        #pragma unroll
        for (int k = 0; k < 8; k++) cmac(acc, X[r * 8 + k], R[k * 8 + c]);
        __syncthreads();
        float inv = 1.f / (float)j;
        R[t] = make_float2(idel + acc.x * inv, acc.y * inv);
        __syncthreads();
    }
    for (int q = 0; q < s; q++) {
        float2 acc = make_float2(0.f, 0.f);
        #pragma unroll
        for (int k = 0; k < 8; k++) cmac(acc, R[r * 8 + k], R[k * 8 + c]);
        __syncthreads();
        R[t] = acc;
        __syncthreads();
    }
    float2 v = R[t];
    if (bid >= 16) {
        float kp = kerr[bid - 16];
        float ang = kp * (float)(r * r);
        float sn, cs; __sincosf(ang, &sn, &cs);
        v = cmul(make_float2(cs, sn), v);
        dpm[(bid - 16) * 64 + c * 8 + r] = v;
    } else {
        sqm[bid * 64 + c * 8 + r] = v;
    }
}

// ---------------------------------------------------------------------------
// Kernel 3: 64x64 complex expm for 48 beamsplitters, diag rotations folded.
// Output: compact photon-number-sparse layout, fixed stride 8 (zero-padded):
//   bsG[blk*512 + o*8 + j] = U'[o][k], k=(amin+j)*8 + (n-amin-j), j<c(n(o)).
// ---------------------------------------------------------------------------
__global__ __launch_bounds__(256) void expm64_kernel(
    const float* __restrict__ th1, const float* __restrict__ ph1,
    const float* __restrict__ th2, const float* __restrict__ ph2,
    float2* __restrict__ bsG) {
    __shared__ float2 X[4096], R[4096];
    int blk = blockIdx.x;
    int l = blk / 12, idx = blk % 12;
    int p = (idx < 6) ? idx : idx - 6;
    int mi = (p < 3) ? 0 : ((p < 5) ? 1 : 2);
    int mj = (p == 0) ? 1 : ((p == 1 || p == 3) ? 2 : 3);
    const float* th = (idx < 6) ? th1 : th2;
    const float* ph = (idx < 6) ? ph1 : ph2;
    float tt = th[l * 16 + mi * 4 + mj];
    float pp = ph[l * 16 + mi * 4 + mj];
    float cp = cosf(pp), sp = sinf(pp);
    float php = ph[l * 16 + mj * 4 + mi];
    float pre_i = 0.f, pre_j = 0.f;
    if (p == 0) { pre_i = ph[l * 16 + 0]; pre_j = ph[l * 16 + 5]; }
    else if (p == 1) { pre_j = ph[l * 16 + 10]; }
    else if (p == 2) { pre_j = ph[l * 16 + 15]; }
    int t = threadIdx.x;
    float normb = fabsf(tt) * 13.94f;
    int s = 0;
    while (normb > 0.2f && s < 20) { normb *= 0.5f; s++; }
    float fs = 1.f;
    for (int q = 0; q < s; q++) fs *= 0.5f;
    for (int e = t; e < 4096; e += 256) {
        int r = e >> 6, c = e & 63;
        int a = r >> 3, b = r & 7, ca = c >> 3, cb = c & 7;
        float2 h = make_float2(0.f, 0.f);
        if (ca == a + 1 && cb == b - 1) {
            float g = tt * sqrtf((float)((a + 1) * b));
            h.x = g * cp; h.y = g * sp;
        } else if (ca == a - 1 && cb == b + 1) {
            float g = tt * sqrtf((float)(a * (b + 1)));
            h.x = -g * cp; h.y = g * sp;
        }
        float2 xs = make_float2(h.x * fs, h.y * fs);
        X[e] = xs;
        R[e] = make_float2(((r == c) ? 1.f : 0.f) + xs.x * 0.1f, xs.y * 0.1f);
    }
    __syncthreads();
    float2 acc[16];
    for (int j = 9; j >= 1; j--) {
        int q = 0;
        for (int e = t; e < 4096; e += 256, q++) {
            int r = e >> 6, c = e & 63;
            float2 a2 = make_float2(0.f, 0.f);
            for (int k = 0; k < 64; k++) cmac(a2, X[r * 64 + k], R[k * 64 + c]);
            acc[q] = a2;
        }
        __syncthreads();
        float inv = 1.f / (float)j;
        q = 0;
        for (int e = t; e < 4096; e += 256, q++) {
            int r = e >> 6, c = e & 63;
            R[e] = make_float2(((r == c) ? 1.f : 0.f) + acc[q].x * inv, acc[q].y * inv);
        }
        __syncthreads();
    }
    for (int sq = 0; sq < s; sq++) {
        int q = 0;
        for (int e = t; e < 4096; e += 256, q++) {
            int r = e >> 6, c = e & 63;
            float2 a2 = make_float2(0.f, 0.f);
            for (int k = 0; k < 64; k++) cmac(a2, R[r * 64 + k], R[k * 64 + c]);
            acc[q] = a2;
        }
        __syncthreads();
        q = 0;
        for (int e = t; e < 4096; e += 256, q++) R[e] = acc[q];
        __syncthreads();
    }
    for (int e = t; e < 512; e += 256) {
        int o = e >> 3, j = e & 7;
        int n = (o >> 3) + (o & 7);
        int amin = max(0, n - 7);
        int cnt = min(n + 1, 15 - n);
        float2 v = make_float2(0.f, 0.f);
        if (j < cnt) {
            int ka = amin + j, kb = n - ka;
            int k = ka * 8 + kb;
            float ang = php * (float)(o & 7) + pre_i * (float)ka + pre_j * (float)kb;
            float sn, cs; __sincosf(ang, &sn, &cs);
            v = cmul(make_float2(cs, sn), R[o * 64 + k]);
        }
        bsG[blk * 512 + o * 8 + j] = v;
    }
}

// ---------------------------------------------------------------------------
// Main simulation kernel. 1 block (256 thr) / 2 samples. Sample A in
// S[0..4095], sample B in S[4096..8191]. 4 waves: wave wq handles sample
// wq>>1, BS output rows 4(wq&1)..4(wq&1)+3 (32 accumulators).
// ---------------------------------------------------------------------------

// Sparse two-mode gate: wave owns 4 output rows of ONE sample. Each LDS read
// (ka, n-ka) feeds up to 4 outputs (a', n-a'), a' in row group. All offsets
// compile-time; per-output accumulation order = ka ascending (bit-identical).
template<int M1, int M2, int RG, int N, int KA>
__device__ __forceinline__ void bs_step(
    Acc16& aL, Acc16& aH, const float2* S,
    const float2* __restrict__ Gt, int pbs) {
    constexpr int st1 = 512 >> (3 * M1);
    constexpr int st2 = 512 >> (3 * M2);
    constexpr int amin = (N > 7) ? (N - 7) : 0;
    constexpr int kamax = (N < 7) ? N : 7;
    if constexpr (KA >= amin && KA <= kamax) {
        constexpr int pk = physw(KA * st1 + (N - KA) * st2);
        float2 sv = S[pbs ^ pk];
        constexpr int A0 = 4 * RG;
        if constexpr (N - A0 >= 0 && N - A0 <= 7) {
            float2 g = Gt[((A0 + 0) * 8 + (N - A0)) * 8 + (KA - amin)];
            cmac(aL.get<(N - A0 >= 0 && N - A0 <= 7) ? (N - A0) : 0>(), g, sv);
        }
        if constexpr (N - A0 - 1 >= 0 && N - A0 - 1 <= 7) {
            float2 g = Gt[((A0 + 1) * 8 + (N - A0 - 1)) * 8 + (KA - amin)];
            cmac(aL.get<(N - A0 - 1 >= 0 && N - A0 - 1 <= 7) ? (8 + N - A0 - 1) : 0>(), g, sv);
        }
        if constexpr (N - A0 - 2 >= 0 && N - A0 - 2 <= 7) {
            float2 g = Gt[((A0 + 2) * 8 + (N - A0 - 2)) * 8 + (KA - amin)];
            cmac(aH.get<(N - A0 - 2 >= 0 && N - A0 - 2 <= 7) ? (N - A0 - 2) : 0>(), g, sv);
        }
        if constexpr (N - A0 - 3 >= 0 && N - A0 - 3 <= 7) {
            float2 g = Gt[((A0 + 3) * 8 + (N - A0 - 3)) * 8 + (KA - amin)];
            cmac(aH.get<(N - A0 - 3 >= 0 && N - A0 - 3 <= 7) ? (8 + N - A0 - 3) : 0>(), g, sv);
        }
    }
    if constexpr (KA < 7) bs_step<M1, M2, RG, N, KA + 1>(aL, aH, S, Gt, pbs);
    else if constexpr (N < 4 * RG + 10) bs_step<M1, M2, RG, N + 1, 0>(aL, aH, S, Gt, pbs);
}

template<int M1, int M2, int RG, int J>
__device__ __forceinline__ void bs_wb(Acc16& aL, Acc16& aH, float2* S, int pbs) {
    constexpr int st1 = 512 >> (3 * M1);
    constexpr int st2 = 512 >> (3 * M2);
    constexpr int r = J >> 3, bb = J & 7;
    constexpr int po = physw((4 * RG + r) * st1 + bb * st2);
    if constexpr (J < 16) S[pbs ^ po] = aL.get<(J < 16) ? J : 0>();
    else                  S[pbs ^ po] = aH.get<(J >= 16) ? (J - 16) : 0>();
    if constexpr (J < 31) bs_wb<M1, M2, RG, J + 1>(aL, aH, S, pbs);
}

template<int M1, int M2, int RG>
__device__ __forceinline__ void bs_gate(
    float2* S, const float2* __restrict__ Gt, int lane, int soff) {
    constexpr int freeA = (M1 != 0 && M2 != 0) ? 0 : ((M1 != 1 && M2 != 1) ? 1 : 2);
    constexpr int freeB = (M1 != 3 && M2 != 3) ? 3 : ((M1 != 2 && M2 != 2) ? 2 : 1);
    constexpr int sa = 512 >> (3 * freeA);
    constexpr int sb = 512 >> (3 * freeB);
    int fbase = (lane >> 3) * sa + (lane & 7) * sb;
    int pbs = physw(fbase) + soff;          // soff = sample*4096 (bit 12)
    Acc16 aL, aH;
    aL.zero(); aH.zero();
    bs_step<M1, M2, RG, 4 * RG, 0>(aL, aH, S, Gt, pbs);
    __syncthreads();
    bs_wb<M1, M2, RG, 0>(aL, aH, S, pbs);
    __syncthreads();
}

template<int M1, int M2>
__device__ __forceinline__ void do_bs(float2* S, const float2* __restrict__ Gt,
                                      int lane, int rg, int soff) {
    if (rg == 0) bs_gate<M1, M2, 0>(S, Gt, lane, soff);
    else         bs_gate<M1, M2, 1>(S, Gt, lane, soff);
}

// Single-mode 8x8 dense gate; thread owns 2 fibers per sample (both samples).
template<int MODE, int K, int I>
__device__ __forceinline__ void og_i(Acc16& accA, Acc16& accB,
                                     float2 s0A, float2 s1A,
                                     float2 s0B, float2 s1B,
                                     const float2* __restrict__ Ut) {
    float2 g = Ut[K * 8 + I];
    cmac(accA.get<I>(), g, s0A);
    cmac(accA.get<8 + I>(), g, s1A);
    cmac(accB.get<I>(), g, s0B);
    cmac(accB.get<8 + I>(), g, s1B);
    if constexpr (I < 7) og_i<MODE, K, I + 1>(accA, accB, s0A, s1A, s0B, s1B, Ut);
}

template<int MODE, int K>
__device__ __forceinline__ void og_k(Acc16& accA, Acc16& accB, const float2* S,
                                     const float2* __restrict__ Ut,
                                     int pb0, int pb1) {
    constexpr int st = 512 >> (3 * MODE);
    constexpr int pk = physw(K * st);
    float2 s0A = S[pb0 ^ pk];
    float2 s1A = S[pb1 ^ pk];
    float2 s0B = S[(pb0 ^ pk) + 4096];
    float2 s1B = S[(pb1 ^ pk) + 4096];
    og_i<MODE, K, 0>(accA, accB, s0A, s1A, s0B, s1B, Ut);
    if constexpr (K < 7) og_k<MODE, K + 1>(accA, accB, S, Ut, pb0, pb1);
}

template<int MODE, int I>
__device__ __forceinline__ void og_wb(Acc16& accA, Acc16& accB, float2* S,
                                      int pb0, int pb1) {
    constexpr int st = 512 >> (3 * MODE);
    constexpr int pi = physw(I * st);
    S[pb0 ^ pi] = accA.get<I>();
    S[pb1 ^ pi] = accA.get<8 + I>();
    S[(pb0 ^ pi) + 4096] = accB.get<I>();
    S[(pb1 ^ pi) + 4096] = accB.get<8 + I>();
    if constexpr (I < 7) og_wb<MODE, I + 1>(accA, accB, S, pb0, pb1);
}

template<int MODE>
__device__ __forceinline__ void one_gate(
    float2* S, const float2* __restrict__ Ut, int t) {
    constexpr int F0 = (MODE == 0) ? 64 : 512;
    constexpr int F1 = (MODE <= 1) ? 8 : 64;
    constexpr int F2 = (MODE == 3) ? 8 : 1;
    int f0 = t, f1 = t + 256;
    int fb0 = ((f0 >> 6) & 7) * F0 + ((f0 >> 3) & 7) * F1 + (f0 & 7) * F2;
    int fb1 = ((f1 >> 6) & 7) * F0 + ((f1 >> 3) & 7) * F1 + (f1 & 7) * F2;
    int pb0 = physw(fb0), pb1 = physw(fb1);
    Acc16 accA, accB;
    accA.zero(); accB.zero();
    og_k<MODE, 0>(accA, accB, S, Ut, pb0, pb1);
    og_wb<MODE, 0>(accA, accB, S, pb0, pb1);
    __syncthreads();
}

__global__ __launch_bounds__(256, 2) void sim_kernel(
    const float* __restrict__ coh, const float2* __restrict__ sqm,
    const float2* __restrict__ dpm, const float2* __restrict__ bsG,
    float* __restrict__ out) {
    __shared__ float2 S[2 * AMPS];   // 65,536 B -> 2 blocks/CU
    int b = blockIdx.x;              // samples 2b, 2b+1
    int t = threadIdx.x;
    int lane = t & 63;
    int wq = __builtin_amdgcn_readfirstlane(t >> 6);
    int rg = wq & 1;                 // BS row group
    int soff = (wq >> 1) * 4096;     // BS sample offset

    // Init both samples. For e = t + 256k: i0=k>>1, i1=(t>>6)+4(k&1),
    // i2=(t>>3)&7, i3=t&7.
    {
        const float* cbA = coh + (2 * b) * 32;
        const float* cbB = cbA + 32;
        float c23A = cbA[16 + ((t >> 3) & 7)] * cbA[24 + (t & 7)];
        float c1aA = cbA[8 + (t >> 6)], c1bA = cbA[8 + (t >> 6) + 4];
        float c23B = cbB[16 + ((t >> 3) & 7)] * cbB[24 + (t & 7)];
        float c1aB = cbB[8 + (t >> 6)], c1bB = cbB[8 + (t >> 6) + 4];
        #pragma unroll
        for (int k = 0; k < 16; k++) {
            int pe = physw(t + 256 * k);
            float vA = cbA[k >> 1] * ((k & 1) ? c1bA : c1aA) * c23A;
            float vB = cbB[k >> 1] * ((k & 1) ? c1bB : c1aB) * c23B;
            S[pe] = make_float2(vA, 0.f);
            S[pe + 4096] = make_float2(vB, 0.f);
        }
    }
    __syncthreads();

    #pragma unroll 1
    for (int l = 0; l < NL; l++) {
        #pragma unroll 1
        for (int h = 0; h < 2; h++) {
            const float2* g = bsG + (size_t)(l * 12 + h * 6) * 512;
            do_bs<0, 1>(S, g + 0 * 512, lane, rg, soff);
            do_bs<0, 2>(S, g + 1 * 512, lane, rg, soff);
            do_bs<0, 3>(S, g + 2 * 512, lane, rg, soff);
            do_bs<1, 2>(S, g + 3 * 512, lane, rg, soff);
            do_bs<1, 3>(S, g + 4 * 512, lane, rg, soff);
            do_bs<2, 3>(S, g + 5 * 512, lane, rg, soff);
            const float2* u = ((h == 0) ? sqm : dpm) + (size_t)(l * 4) * 64;
            one_gate<0>(S, u + 0 * 64, t);
            one_gate<1>(S, u + 1 * 64, t);
            one_gate<2>(S, u + 2 * 64, t);
            one_gate<3>(S, u + 3 * 64, t);
        }
    }

    // <n_w> per mode, both samples.
    float eA0 = 0.f, eA1 = 0.f, eA2 = 0.f, eA3 = 0.f;
    float eB0 = 0.f, eB1 = 0.f, eB2 = 0.f, eB3 = 0.f;
    for (int e = t; e < AMPS; e += 256) {
        int pe = physw(e);
        float2 sA = S[pe];
        float2 sB = S[pe + 4096];
        float prA = sA.x * sA.x + sA.y * sA.y;
        float prB = sB.x * sB.x + sB.y * sB.y;
        float n0 = (float)(e >> 9), n1 = (float)((e >> 6) & 7);
        float n2 = (float)((e >> 3) & 7), n3 = (float)(e & 7);
        eA0 += prA * n0; eA1 += prA * n1; eA2 += prA * n2; eA3 += prA * n3;
        eB0 += prB * n0; eB1 += prB * n1; eB2 += prB * n2; eB3 += prB * n3;
    }
    #pragma unroll
    for (int off = 32; off > 0; off >>= 1) {
        eA0 += __shfl_down(eA0, off); eA1 += __shfl_down(eA1, off);
        eA2 += __shfl_down(eA2, off); eA3 += __shfl_down(eA3, off);
        eB0 += __shfl_down(eB0, off); eB1 += __shfl_down(eB1, off);
        eB2 += __shfl_down(eB2, off); eB3 += __shfl_down(eB3, off);
    }
    __syncthreads();              // all S reads done; S storage now dead
    float* redf = (float*)S;      // overlay 32-float reduction buffer on S
    if (lane == 0) {
        redf[wq * 8 + 0] = eA0; redf[wq * 8 + 1] = eA1;
        redf[wq * 8 + 2] = eA2; redf[wq * 8 + 3] = eA3;
        redf[wq * 8 + 4] = eB0; redf[wq * 8 + 5] = eB1;
        redf[wq * 8 + 6] = eB2; redf[wq * 8 + 7] = eB3;
    }
    __syncthreads();
    if (t < 4) {
        float s = redf[t] + redf[8 + t] + redf[16 + t] + redf[24 + t];
        out[(2 * b) * 4 + t] = s;
    } else if (t < 8) {
        int tt = t - 4;
        float s = redf[4 + tt] + redf[12 + tt] + redf[20 + tt] + redf[28 + tt];
        out[(2 * b + 1) * 4 + tt] = s;
    }
}

extern "C" void kernel_launch(void* const* d_in, const int* in_sizes, int n_in,
                              void* d_out, int out_size, void* d_ws, size_t ws_size,
                              hipStream_t stream) {
    const float* x    = (const float*)d_in[0];
    const float* th1  = (const float*)d_in[1];
    const float* ph1  = (const float*)d_in[2];
    const float* th2  = (const float*)d_in[3];
    const float* ph2  = (const float*)d_in[4];
    const float* dpr  = (const float*)d_in[5];
    const float* dpph = (const float*)d_in[6];
    const float* sqr  = (const float*)d_in[7];
    const float* sqph = (const float*)d_in[8];
    const float* kerr = (const float*)d_in[9];
    float* out = (float*)d_out;

    int Bn = in_sizes[0] / NM;

    char* ws = (char*)d_ws;
    float*  coh = (float*)ws;                          // Bn*32 floats
    size_t coh_bytes = (size_t)Bn * 32 * sizeof(float);
    float2* sqm = (float2*)(ws + coh_bytes);           // 16*64 float2
    float2* dpm = (float2*)(ws + coh_bytes + 16 * 64 * sizeof(float2));
    float2* bsG = (float2*)(ws + coh_bytes + 32 * 64 * sizeof(float2)); // 48*512 float2

    int total = Bn * NM;
    coh_kernel<<<(total + 255) / 256, 256, 0, stream>>>(x, coh, total);
    expm8_kernel<<<32, 64, 0, stream>>>(sqr, sqph, dpr, dpph, kerr, sqm, dpm);
    expm64_kernel<<<48, 256, 0, stream>>>(th1, ph1, th2, ph2, bsG);
    sim_kernel<<<Bn / 2, 256, 0, stream>>>(coh, sqm, dpm, bsG, out);
}

// Round 8
// 2240.816 us; speedup vs baseline: 1.2177x; 1.2177x over previous
//
#include <hip/hip_runtime.h>

// CV quantum neural network simulator, D=8 cutoff, M=4 modes, L=4 layers.
// R12: one wave per sample, full state in registers (64 float2/lane).
// Rationale: R4-R11 pinned VALUBusy at ~40% across occupancy 22-88% and
// traffic 38MB-6GB -> limiter is the barrier-locked ds-chain structure +
// ~80-160KB unrolled loop body streaming through 32KB L1I. New structure:
// gates on reg-dim mode pairs are lane-local (pure register FMA, coeffs via
// wave-uniform s_load); mode pairs rotated into regs by in-wave partial
// transposes (8 hazard-free rounds of 8 ds_write/lgkm/8 ds_read through a
// private 4.6KB LDS buffer). NO __syncthreads at all. Legal gate reorder
// (BS03<->BS12 disjoint; ogs commute) gives 8 swaps per half-layer and a
// layout cycle that returns to canonical. BS body is ONE code instance in a
// 6-iter loop (~20KB, L1I-resident); ogs are two 2-iter loops. Per-output
// accumulation order (ka ascending) preserved.

#define NM 4
#define NL 4

__device__ __forceinline__ void cmac(float2& acc, float2 a, float2 b) {
    acc.x = fmaf(a.x, b.x, acc.x);
    acc.x = fmaf(-a.y, b.y, acc.x);
    acc.y = fmaf(a.x, b.y, acc.y);
    acc.y = fmaf(a.y, b.x, acc.y);
}
__device__ __forceinline__ float2 cmul(float2 a, float2 b) {
    return make_float2(a.x * b.x - a.y * b.y, a.x * b.y + a.y * b.x);
}

// ---------------------------------------------------------------------------
// Kernel 1: coherent vectors = first column of expm(x*(AD - A)).
// ---------------------------------------------------------------------------
__global__ void coh_kernel(const float* __restrict__ x, float* __restrict__ coh, int total) {
    int t = blockIdx.x * blockDim.x + threadIdx.x;
    if (t >= total) return;
    float alpha = x[t];
    const float sq1 = 1.0f, sq2 = 1.41421356f, sq3 = 1.73205081f, sq4 = 2.0f,
                sq5 = 2.23606798f, sq6 = 2.44948975f, sq7 = 2.64575131f;
    float v0 = 1.f, v1 = 0.f, v2 = 0.f, v3 = 0.f, v4 = 0.f, v5 = 0.f, v6 = 0.f, v7 = 0.f;
    const int NS = 32;
    float h = alpha / (float)NS;
    for (int s = 0; s < NS; s++) {
        float w0 = v0, w1 = v1, w2 = v2, w3 = v3, w4 = v4, w5 = v5, w6 = v6, w7 = v7;
        float t0 = v0, t1 = v1, t2 = v2, t3 = v3, t4 = v4, t5 = v5, t6 = v6, t7 = v7;
        #pragma unroll
        for (int j = 1; j <= 8; j++) {
            float c = h / (float)j;
            float n0 = c * (          - sq1 * t1);
            float n1 = c * (sq1 * t0 - sq2 * t2);
            float n2 = c * (sq2 * t1 - sq3 * t3);
            float n3 = c * (sq3 * t2 - sq4 * t4);
            float n4 = c * (sq4 * t3 - sq5 * t5);
            float n5 = c * (sq5 * t4 - sq6 * t6);
            float n6 = c * (sq6 * t5 - sq7 * t7);
            float n7 = c * (sq7 * t6            );
            t0 = n0; t1 = n1; t2 = n2; t3 = n3; t4 = n4; t5 = n5; t6 = n6; t7 = n7;
            w0 += t0; w1 += t1; w2 += t2; w3 += t3; w4 += t4; w5 += t5; w6 += t6; w7 += t7;
        }
        v0 = w0; v1 = w1; v2 = w2; v3 = w3; v4 = w4; v5 = w5; v6 = w6; v7 = w7;
    }
    float* dst = coh + t * 8;
    dst[0] = v0; dst[1] = v1; dst[2] = v2; dst[3] = v3;
    dst[4] = v4; dst[5] = v5; dst[6] = v6; dst[7] = v7;
}

// ---------------------------------------------------------------------------
// Kernel 2: 8x8 complex expm. Blocks 0..15: squeeze. Blocks 16..31:
// displacement with Kerr folded (row scale). Stored transposed [k*8+i].
// ---------------------------------------------------------------------------
__global__ __launch_bounds__(64) void expm8_kernel(
    const float* __restrict__ sqr, const float* __restrict__ sqph,
    const float* __restrict__ dpr, const float* __restrict__ dpph,
    const float* __restrict__ kerr,
    float2* __restrict__ sqm, float2* __restrict__ dpm) {
    __shared__ float2 X[64], R[64];
    int t = threadIdx.x;
    int r = t >> 3, c = t & 7;
    int bid = blockIdx.x;
    float2 h = make_float2(0.f, 0.f);
    float normb;
    if (bid < 16) {
        float rr = sqr[bid], ph = sqph[bid];
        float zr = rr * cosf(ph), zi = rr * sinf(ph);
        if (c == r + 2) { float f = 0.5f * sqrtf((float)((r + 1) * (r + 2))); h.x =  f * zr; h.y = -f * zi; }
        if (r == c + 2) { float f = 0.5f * sqrtf((float)((c + 1) * (c + 2))); h.x = -f * zr; h.y = -f * zi; }
        normb = fabsf(rr) * 5.5f;
    } else {
        int g = bid - 16;
        float rr = dpr[g], ph = dpph[g];
        float am = rr * cosf(ph);
        float aph = rr * sinf(ph);
        float ar = am * cosf(aph), ai = am * sinf(aph);
        if (r == c + 1) { float f = sqrtf((float)r); h.x += ar * f; h.y += ai * f; }
        if (c == r + 1) { float f = sqrtf((float)c); h.x -= ar * f; h.y += ai * f; }
        normb = fabsf(am) * 5.5f;
    }
    int s = 0;
    while (normb > 0.2f && s < 20) { normb *= 0.5f; s++; }
    float fs = 1.f;
    for (int q = 0; q < s; q++) fs *= 0.5f;
    float2 xs = make_float2(h.x * fs, h.y * fs);
    X[t] = xs;
    float idel = (r == c) ? 1.f : 0.f;
    R[t] = make_float2(idel + xs.x / 9.f, xs.y / 9.f);
    __syncthreads();
    for (int j = 8; j >= 1; j--) {
        float2 acc = make_float2(0.f, 0.f);
        #pragma unroll
        for (int k = 0; k < 8; k++) cmac(acc, X[r * 8 + k], R[k * 8 + c]);
        __syncthreads();
        float inv = 1.f / (float)j;
        R[t] = make_float2(idel + acc.x * inv, acc.y * inv);
        __syncthreads();
    }
    for (int q = 0; q < s; q++) {
        float2 acc = make_float2(0.f, 0.f);
        #pragma unroll
        for (int k = 0; k < 8; k++) cmac(acc, R[r * 8 + k], R[k * 8 + c]);
        __syncthreads();
        R[t] = acc;
        __syncthreads();
    }
    float2 v = R[t];
    if (bid >= 16) {
        float kp = kerr[bid - 16];
        float ang = kp * (float)(r * r);
        float sn, cs; __sincosf(ang, &sn, &cs);
        v = cmul(make_float2(cs, sn), v);
        dpm[(bid - 16) * 64 + c * 8 + r] = v;
    } else {
        sqm[bid * 64 + c * 8 + r] = v;
    }
}

// ---------------------------------------------------------------------------
// Kernel 3: 64x64 complex expm for 48 beamsplitters, diag rotations folded.
// Output: compact photon-number-sparse layout, fixed stride 8 (zero-padded):
//   bsG[blk*512 + o*8 + j] = U'[o][k], k=(amin+j)*8 + (n-amin-j), j<c(n(o)).
// ---------------------------------------------------------------------------
__global__ __launch_bounds__(256) void expm64_kernel(
    const float* __restrict__ th1, const float* __restrict__ ph1,
    const float* __restrict__ th2, const float* __restrict__ ph2,
    float2* __restrict__ bsG) {
    __shared__ float2 X[4096], R[4096];
    int blk = blockIdx.x;
    int l = blk / 12, idx = blk % 12;
    int p = (idx < 6) ? idx : idx - 6;
    int mi = (p < 3) ? 0 : ((p < 5) ? 1 : 2);
    int mj = (p == 0) ? 1 : ((p == 1 || p == 3) ? 2 : 3);
    const float* th = (idx < 6) ? th1 : th2;
    const float* ph = (idx < 6) ? ph1 : ph2;
    float tt = th[l * 16 + mi * 4 + mj];
    float pp = ph[l * 16 + mi * 4 + mj];
    float cp = cosf(pp), sp = sinf(pp);
    float php = ph[l * 16 + mj * 4 + mi];
    float pre_i = 0.f, pre_j = 0.f;
    if (p == 0) { pre_i = ph[l * 16 + 0]; pre_j = ph[l * 16 + 5]; }
    else if (p == 1) { pre_j = ph[l * 16 + 10]; }
    else if (p == 2) { pre_j = ph[l * 16 + 15]; }
    int t = threadIdx.x;
    float normb = fabsf(tt) * 13.94f;
    int s = 0;
    while (normb > 0.2f && s < 20) { normb *= 0.5f; s++; }
    float fs = 1.f;
    for (int q = 0; q < s; q++) fs *= 0.5f;
    for (int e = t; e < 4096; e += 256) {
        int r = e >> 6, c = e & 63;
        int a = r >> 3, b = r & 7, ca = c >> 3, cb = c & 7;
        float2 h = make_float2(0.f, 0.f);
        if (ca == a + 1 && cb == b - 1) {
            float g = tt * sqrtf((float)((a + 1) * b));
            h.x = g * cp; h.y = g * sp;
        } else if (ca == a - 1 && cb == b + 1) {
            float g = tt * sqrtf((float)(a * (b + 1)));
            h.x = -g * cp; h.y = g * sp;
        }
        float2 xs = make_float2(h.x * fs, h.y * fs);
        X[e] = xs;
        R[e] = make_float2(((r == c) ? 1.f : 0.f) + xs.x * 0.1f, xs.y * 0.1f);
    }
    __syncthreads();
    float2 acc[16];
    for (int j = 9; j >= 1; j--) {
        int q = 0;
        for (int e = t; e < 4096; e += 256, q++) {
            int r = e >> 6, c = e & 63;
            float2 a2 = make_float2(0.f, 0.f);
            for (int k = 0; k < 64; k++) cmac(a2, X[r * 64 + k], R[k * 64 + c]);
            acc[q] = a2;
        }
        __syncthreads();
        float inv = 1.f / (float)j;
        q = 0;
        for (int e = t; e < 4096; e += 256, q++) {
            int r = e >> 6, c = e & 63;
            R[e] = make_float2(((r == c) ? 1.f : 0.f) + acc[q].x * inv, acc[q].y * inv);
        }
        __syncthreads();
    }
    for (int sq = 0; sq < s; sq++) {
        int q = 0;
        for (int e = t; e < 4096; e += 256, q++) {
            int r = e >> 6, c = e & 63;
            float2 a2 = make_float2(0.f, 0.f);
            for (int k = 0; k < 64; k++) cmac(a2, R[r * 64 + k], R[k * 64 + c]);
            acc[q] = a2;
        }
        __syncthreads();
        q = 0;
        for (int e = t; e < 4096; e += 256, q++) R[e] = acc[q];
        __syncthreads();
    }
    for (int e = t; e < 512; e += 256) {
        int o = e >> 3, j = e & 7;
        int n = (o >> 3) + (o & 7);
        int amin = max(0, n - 7);
        int cnt = min(n + 1, 15 - n);
        float2 v = make_float2(0.f, 0.f);
        if (j < cnt) {
            int ka = amin + j, kb = n - ka;
            int k = ka * 8 + kb;
            float ang = php * (float)(o & 7) + pre_i * (float)ka + pre_j * (float)kb;
            float sn, cs; __sincosf(ang, &sn, &cs);
            v = cmul(make_float2(cs, sn), R[o * 64 + k]);
        }
        bsG[blk * 512 + o * 8 + j] = v;
    }
}

// ---------------------------------------------------------------------------
// Main simulation kernel: 1 wave = 1 sample; state = 64 float2 per lane.
// Layout [Lhi Llo | Rhi Rlo]: lane = i_Lhi*8+i_Llo, reg r = i_Rhi*8+i_Rlo.
// Canonical layout (2 3 | 0 1).
// ---------------------------------------------------------------------------

// Two-mode BS gate on the in-register 8x8 tile (reg dims = (mi, mj) ordered).
__device__ __forceinline__ void bs_apply(const float2* __restrict__ Gt,
                                         float2 (&V)[64]) {
    #pragma unroll
    for (int n = 0; n < 15; ++n) {
        const int amin = (n > 7) ? (n - 7) : 0;
        const int amax = (n < 7) ? n : 7;
        const int cnt = amax - amin + 1;
        float2 tin[8], tout[8];
        #pragma unroll
        for (int k = 0; k < 8; ++k)
            if (k < cnt) tin[k] = V[(amin + k) * 8 + (n - amin - k)];
        #pragma unroll
        for (int j = 0; j < 8; ++j) if (j < cnt) {
            const int o = (amin + j) * 8 + (n - amin - j);
            float2 acc = make_float2(0.f, 0.f);
            #pragma unroll
            for (int k = 0; k < 8; ++k)
                if (k < cnt) cmac(acc, Gt[o * 8 + k], tin[k]);
            tout[j] = acc;
        }
        #pragma unroll
        for (int j = 0; j < 8; ++j)
            if (j < cnt) V[(amin + j) * 8 + (n - amin - j)] = tout[j];
    }
}

// Single-mode gate on reg slot (0 = hi/stride-8, 1 = lo/stride-1).
template<int SLOT>
__device__ __forceinline__ void og_apply(const float2* __restrict__ Ut,
                                         float2 (&V)[64]) {
    #pragma unroll
    for (int f = 0; f < 8; ++f) {
        float2 tin[8], tout[8];
        #pragma unroll
        for (int k = 0; k < 8; ++k) tin[k] = V[SLOT == 0 ? k * 8 + f : f * 8 + k];
        #pragma unroll
        for (int i = 0; i < 8; ++i) {
            float2 acc = make_float2(0.f, 0.f);
            #pragma unroll
            for (int k = 0; k < 8; ++k) cmac(acc, Ut[k * 8 + i], tin[k]);
            tout[i] = acc;
        }
        #pragma unroll
        for (int i = 0; i < 8; ++i) V[SLOT == 0 ? i * 8 + f : f * 8 + i] = tout[i];
    }
}

// Swap lane-slot SL mode with reg-slot SR mode. In-wave only (no barrier):
// 8 rounds over the kept reg comp d: write 8, lgkmcnt, read 8, lgkmcnt.
// lbuf layout [a][x][y]: a*72 + x*9 + y (float2), 576 float2 per wave.
template<int SL, int SR>
__device__ __forceinline__ void lane_swap(float2* __restrict__ lbuf,
                                          float2 (&V)[64], int lane) {
    int a = (SL == 0) ? (lane & 7) : (lane >> 3);   // kept lane comp
    int m = (SL == 0) ? (lane >> 3) : (lane & 7);   // swapped lane comp
    int wbase = a * 72 + m * 9;
    int rbase = a * 72 + m;
    #pragma unroll
    for (int d = 0; d < 8; ++d) {
        #pragma unroll
        for (int u = 0; u < 8; ++u)
            lbuf[wbase + u] = V[SR == 0 ? u * 8 + d : d * 8 + u];
        asm volatile("s_waitcnt lgkmcnt(0)" ::: "memory");
        #pragma unroll
        for (int u = 0; u < 8; ++u)
            V[SR == 0 ? u * 8 + d : d * 8 + u] = lbuf[rbase + u * 9];
        asm volatile("s_waitcnt lgkmcnt(0)" ::: "memory");
    }
}

__global__ __launch_bounds__(256, 2) void sim_kernel(
    const float* __restrict__ coh, const float2* __restrict__ sqm,
    const float2* __restrict__ dpm, const float2* __restrict__ bsG,
    float* __restrict__ out) {
    __shared__ float2 TB[4 * 584];   // 584-stride staggers wave buffers
    int t = threadIdx.x;
    int lane = t & 63;
    int wq = t >> 6;
    int s = blockIdx.x * 4 + wq;     // sample id
    float2* lbuf = TB + wq * 584;

    float2 V[64];

    // Init, layout (2 3 | 0 1): lane=(i2,i3), reg r=i0*8+i1.
    {
        const float* cb = coh + s * 32;
        float cs = cb[16 + (lane >> 3)] * cb[24 + (lane & 7)];
        #pragma unroll
        for (int i0 = 0; i0 < 8; ++i0) {
            float c0 = cb[i0] * cs;
            #pragma unroll
            for (int i1 = 0; i1 < 8; ++i1)
                V[i0 * 8 + i1] = make_float2(c0 * cb[8 + i1], 0.f);
        }
    }

    #pragma unroll 1
    for (int l = 0; l < NL; ++l) {
        #pragma unroll 1
        for (int h = 0; h < 2; ++h) {
            const float2* gseg = bsG + (size_t)(l * 12 + h * 6) * 512;
            // BS chain (legal reorder 01,02,12,03,13,23), one body, 6 iters.
            #pragma unroll 1
            for (int g = 0; g < 6; ++g) {
                int p = (g == 2) ? 3 : ((g == 3) ? 2 : g);
                bs_apply(gseg + (size_t)p * 512, V);
                switch (g) {
                    case 0: lane_swap<0, 1>(lbuf, V, lane); break;
                    case 1: lane_swap<0, 0>(lbuf, V, lane); break;
                    case 2: lane_swap<1, 1>(lbuf, V, lane);
                            lane_swap<0, 0>(lbuf, V, lane); break;
                    case 3: lane_swap<0, 0>(lbuf, V, lane); break;
                    case 4: lane_swap<1, 0>(lbuf, V, lane); break;
                    default: break;   // g==5: og phase follows at (0 1 | 2 3)
                }
            }
            const float2* u = ((h == 0) ? sqm : dpm) + (size_t)(l * 4) * 64;
            // og2 (Rhi) ; swap -> (2 1 | 0 3) ; og0 (Rhi)
            #pragma unroll 1
            for (int q = 0; q < 2; ++q) {
                og_apply<0>(u + (size_t)(q ? 0 : 2) * 64, V);
                if (q == 0) lane_swap<0, 0>(lbuf, V, lane);
            }
            // og3 (Rlo) ; swap -> (2 3 | 0 1) ; og1 (Rlo)
            #pragma unroll 1
            for (int q = 0; q < 2; ++q) {
                og_apply<1>(u + (size_t)(q ? 1 : 3) * 64, V);
                if (q == 0) lane_swap<1, 1>(lbuf, V, lane);
            }
        }
    }

    // Reduction, layout (2 3 | 0 1): n2 = lane>>3, n3 = lane&7.
    float ev0 = 0.f, ev1 = 0.f, pt = 0.f;
    #pragma unroll
    for (int r = 0; r < 64; ++r) {
        float pr = V[r].x * V[r].x + V[r].y * V[r].y;
        pt += pr;
        ev0 += pr * (float)(r >> 3);
        ev1 += pr * (float)(r & 7);
    }
    float ev2 = pt * (float)(lane >> 3);
    float ev3 = pt * (float)(lane & 7);
    #pragma unroll
    for (int off = 32; off > 0; off >>= 1) {
        ev0 += __shfl_down(ev0, off);
        ev1 += __shfl_down(ev1, off);
        ev2 += __shfl_down(ev2, off);
        ev3 += __shfl_down(ev3, off);
    }
    if (lane == 0) {
        out[s * 4 + 0] = ev0;
        out[s * 4 + 1] = ev1;
        out[s * 4 + 2] = ev2;
        out[s * 4 + 3] = ev3;
    }
}

extern "C" void kernel_launch(void* const* d_in, const int* in_sizes, int n_in,
                              void* d_out, int out_size, void* d_ws, size_t ws_size,
                              hipStream_t stream) {
    const float* x    = (const float*)d_in[0];
    const float* th1  = (const float*)d_in[1];
    const float* ph1  = (const float*)d_in[2];
    const float* th2  = (const float*)d_in[3];
    const float* ph2  = (const float*)d_in[4];
    const float* dpr  = (const float*)d_in[5];
    const float* dpph = (const float*)d_in[6];
    const float* sqr  = (const float*)d_in[7];
    const float* sqph = (const float*)d_in[8];
    const float* kerr = (const float*)d_in[9];
    float* out = (float*)d_out;

    int Bn = in_sizes[0] / NM;

    char* ws = (char*)d_ws;
    float*  coh = (float*)ws;                          // Bn*32 floats
    size_t coh_bytes = (size_t)Bn * 32 * sizeof(float);
    float2* sqm = (float2*)(ws + coh_bytes);           // 16*64 float2
    float2* dpm = (float2*)(ws + coh_bytes + 16 * 64 * sizeof(float2));
    float2* bsG = (float2*)(ws + coh_bytes + 32 * 64 * sizeof(float2)); // 48*512 float2

    int total = Bn * NM;
    coh_kernel<<<(total + 255) / 256, 256, 0, stream>>>(x, coh, total);
    expm8_kernel<<<32, 64, 0, stream>>>(sqr, sqph, dpr, dpph, kerr, sqm, dpm);
    expm64_kernel<<<48, 256, 0, stream>>>(th1, ph1, th2, ph2, bsG);
    sim_kernel<<<Bn / 4, 256, 0, stream>>>(coh, sqm, dpm, bsG, out);
}

// Round 9
// 1543.297 us; speedup vs baseline: 1.7680x; 1.4520x over previous
//
#include <hip/hip_runtime.h>

// CV quantum neural network simulator, D=8 cutoff, M=4 modes, L=4 layers.
// R13: isolate the barrier variable. Base = R8 (named Acc16, zero spill,
// verified). BS gates ping-pong between two 32KB halves of a 64KB S array:
// gate g reads half(g&1), writes half(1-(g&1)) -> the pre-write barrier is
// unnecessary (no one reads the dst half), leaving ONE barrier per BS gate
// (80/block vs 128). The +32768B offset is a compile-time PAR template
// param folding into the 16-bit ds immediate -> zero extra address math.
// 6 flips/half-layer return parity to 0, so one_gate/init/reduction are
// untouched. Accumulation order unchanged -> numerics identical to R8.

#define NM 4
#define NL 4
#define AMPS 4096

__device__ __forceinline__ void cmac(float2& acc, float2 a, float2 b) {
    acc.x = fmaf(a.x, b.x, acc.x);
    acc.x = fmaf(-a.y, b.y, acc.x);
    acc.y = fmaf(a.x, b.y, acc.y);
    acc.y = fmaf(a.y, b.x, acc.y);
}
__device__ __forceinline__ float2 cmul(float2 a, float2 b) {
    return make_float2(a.x * b.x - a.y * b.y, a.x * b.y + a.y * b.x);
}

// F2-linear physical-slot map (bank-conflict-free for all access patterns).
__host__ __device__ constexpr int physw(int e) {
    int l0 = ((e >> 0) ^ (e >> 5) ^ (e >> 7) ^ (e >> 9)) & 1;
    int l1 = ((e >> 1) ^ (e >> 3) ^ (e >> 8) ^ (e >> 10)) & 1;
    int l2 = ((e >> 2) ^ (e >> 4) ^ (e >> 6) ^ (e >> 11)) & 1;
    int l3 = ((e >> 3) ^ (e >> 6) ^ (e >> 9)) & 1;
    return (e & ~15) | l0 | (l1 << 1) | (l2 << 2) | (l3 << 3);
}

// 16 named float2 accumulators -- cannot be demoted to scratch.
struct Acc16 {
    float2 v0,v1,v2,v3,v4,v5,v6,v7,v8,v9,v10,v11,v12,v13,v14,v15;
    template<int I> __device__ __forceinline__ float2& get() {
        if constexpr (I == 0) return v0;  else if constexpr (I == 1) return v1;
        else if constexpr (I == 2) return v2;  else if constexpr (I == 3) return v3;
        else if constexpr (I == 4) return v4;  else if constexpr (I == 5) return v5;
        else if constexpr (I == 6) return v6;  else if constexpr (I == 7) return v7;
        else if constexpr (I == 8) return v8;  else if constexpr (I == 9) return v9;
        else if constexpr (I == 10) return v10; else if constexpr (I == 11) return v11;
        else if constexpr (I == 12) return v12; else if constexpr (I == 13) return v13;
        else if constexpr (I == 14) return v14; else return v15;
    }
    __device__ __forceinline__ void zero() {
        float2 z = make_float2(0.f, 0.f);
        v0=z; v1=z; v2=z; v3=z; v4=z; v5=z; v6=z; v7=z;
        v8=z; v9=z; v10=z; v11=z; v12=z; v13=z; v14=z; v15=z;
    }
};

// ---------------------------------------------------------------------------
// Kernel 1: coherent vectors = first column of expm(x*(AD - A)).
// ---------------------------------------------------------------------------
__global__ void coh_kernel(const float* __restrict__ x, float* __restrict__ coh, int total) {
    int t = blockIdx.x * blockDim.x + threadIdx.x;
    if (t >= total) return;
    float alpha = x[t];
    const float sq1 = 1.0f, sq2 = 1.41421356f, sq3 = 1.73205081f, sq4 = 2.0f,
                sq5 = 2.23606798f, sq6 = 2.44948975f, sq7 = 2.64575131f;
    float v0 = 1.f, v1 = 0.f, v2 = 0.f, v3 = 0.f, v4 = 0.f, v5 = 0.f, v6 = 0.f, v7 = 0.f;
    const int NS = 32;
    float h = alpha / (float)NS;
    for (int s = 0; s < NS; s++) {
        float w0 = v0, w1 = v1, w2 = v2, w3 = v3, w4 = v4, w5 = v5, w6 = v6, w7 = v7;
        float t0 = v0, t1 = v1, t2 = v2, t3 = v3, t4 = v4, t5 = v5, t6 = v6, t7 = v7;
        #pragma unroll
        for (int j = 1; j <= 8; j++) {
            float c = h / (float)j;
            float n0 = c * (          - sq1 * t1);
            float n1 = c * (sq1 * t0 - sq2 * t2);
            float n2 = c * (sq2 * t1 - sq3 * t3);
            float n3 = c * (sq3 * t2 - sq4 * t4);
            float n4 = c * (sq4 * t3 - sq5 * t5);
            float n5 = c * (sq5 * t4 - sq6 * t6);
            float n6 = c * (sq6 * t5 - sq7 * t7);
            float n7 = c * (sq7 * t6            );
            t0 = n0; t1 = n1; t2 = n2; t3 = n3; t4 = n4; t5 = n5; t6 = n6; t7 = n7;
            w0 += t0; w1 += t1; w2 += t2; w3 += t3; w4 += t4; w5 += t5; w6 += t6; w7 += t7;
        }
        v0 = w0; v1 = w1; v2 = w2; v3 = w3; v4 = w4; v5 = w5; v6 = w6; v7 = w7;
    }
    float* dst = coh + t * 8;
    dst[0] = v0; dst[1] = v1; dst[2] = v2; dst[3] = v3;
    dst[4] = v4; dst[5] = v5; dst[6] = v6; dst[7] = v7;
}

// ---------------------------------------------------------------------------
// Kernel 2: 8x8 complex expm. Blocks 0..15: squeeze. Blocks 16..31:
// displacement with Kerr folded (row scale). Stored transposed [k*8+i].
// ---------------------------------------------------------------------------
__global__ __launch_bounds__(64) void expm8_kernel(
    const float* __restrict__ sqr, const float* __restrict__ sqph,
    const float* __restrict__ dpr, const float* __restrict__ dpph,
    const float* __restrict__ kerr,
    float2* __restrict__ sqm, float2* __restrict__ dpm) {
    __shared__ float2 X[64], R[64];
    int t = threadIdx.x;
    int r = t >> 3, c = t & 7;
    int bid = blockIdx.x;
    float2 h = make_float2(0.f, 0.f);
    float normb;
    if (bid < 16) {
        float rr = sqr[bid], ph = sqph[bid];
        float zr = rr * cosf(ph), zi = rr * sinf(ph);
        if (c == r + 2) { float f = 0.5f * sqrtf((float)((r + 1) * (r + 2))); h.x =  f * zr; h.y = -f * zi; }
        if (r == c + 2) { float f = 0.5f * sqrtf((float)((c + 1) * (c + 2))); h.x = -f * zr; h.y = -f * zi; }
        normb = fabsf(rr) * 5.5f;
    } else {
        int g = bid - 16;
        float rr = dpr[g], ph = dpph[g];
        float am = rr * cosf(ph);
        float aph = rr * sinf(ph);
        float ar = am * cosf(aph), ai = am * sinf(aph);
        if (r == c + 1) { float f = sqrtf((float)r); h.x += ar * f; h.y += ai * f; }
        if (c == r + 1) { float f = sqrtf((float)c); h.x -= ar * f; h.y += ai * f; }
        normb = fabsf(am) * 5.5f;
    }
    int s = 0;
    while (normb > 0.2f && s < 20) { normb *= 0.5f; s++; }
    float fs = 1.f;
    for (int q = 0; q < s; q++) fs *= 0.5f;
    float2 xs = make_float2(h.x * fs, h.y * fs);
    X[t] = xs;
    float idel = (r == c) ? 1.f : 0.f;
    R[t] = make_float2(idel + xs.x / 9.f, xs.y / 9.f);
    __syncthreads();
    for (int j = 8; j >= 1; j--) {
        float2 acc = make_float2(0.f, 0.f);
        #pragma unroll
        for (int k = 0; k < 8; k++) cmac(acc, X[r * 8 + k], R[k * 8 + c]);
        __syncthreads();
        float inv = 1.f / (float)j;
        R[t] = make_float2(idel + acc.x * inv, acc.y * inv);
        __syncthreads();
    }
    for (int q = 0; q < s; q++) {
        float2 acc = make_float2(0.f, 0.f);
        #pragma unroll
        for (int k = 0; k < 8; k++) cmac(acc, R[r * 8 + k], R[k * 8 + c]);
        __syncthreads();
        R[t] = acc;
        __syncthreads();
    }
    float2 v = R[t];
    if (bid >= 16) {
        float kp = kerr[bid - 16];
        float ang = kp * (float)(r * r);
        float sn, cs; __sincosf(ang, &sn, &cs);
        v = cmul(make_float2(cs, sn), v);
        dpm[(bid - 16) * 64 + c * 8 + r] = v;
    } else {
        sqm[bid * 64 + c * 8 + r] = v;
    }
}

// ---------------------------------------------------------------------------
// Kernel 3: 64x64 complex expm for 48 beamsplitters, diag rotations folded.
// Output: compact photon-number-sparse layout, fixed stride 8 (zero-padded):
//   bsG[blk*512 + o*8 + j] = U'[o][k], k=(amin+j)*8 + (n-amin-j), j<c(n(o)).
// ---------------------------------------------------------------------------
__global__ __launch_bounds__(256) void expm64_kernel(
    const float* __restrict__ th1, const float* __restrict__ ph1,
    const float* __restrict__ th2, const float* __restrict__ ph2,
    float2* __restrict__ bsG) {
    __shared__ float2 X[4096], R[4096];
    int blk = blockIdx.x;
    int l = blk / 12, idx = blk % 12;
    int p = (idx < 6) ? idx : idx - 6;
    int mi = (p < 3) ? 0 : ((p < 5) ? 1 : 2);
    int mj = (p == 0) ? 1 : ((p == 1 || p == 3) ? 2 : 3);
    const float* th = (idx < 6) ? th1 : th2;
    const float* ph = (idx < 6) ? ph1 : ph2;
    float tt = th[l * 16 + mi * 4 + mj];
    float pp = ph[l * 16 + mi * 4 + mj];
    float cp = cosf(pp), sp = sinf(pp);
    float php = ph[l * 16 + mj * 4 + mi];
    float pre_i = 0.f, pre_j = 0.f;
    if (p == 0) { pre_i = ph[l * 16 + 0]; pre_j = ph[l * 16 + 5]; }
    else if (p == 1) { pre_j = ph[l * 16 + 10]; }
    else if (p == 2) { pre_j = ph[l * 16 + 15]; }
    int t = threadIdx.x;
    float normb = fabsf(tt) * 13.94f;
    int s = 0;
    while (normb > 0.2f && s < 20) { normb *= 0.5f; s++; }
    float fs = 1.f;
    for (int q = 0; q < s; q++) fs *= 0.5f;
    for (int e = t; e < 4096; e += 256) {
        int r = e >> 6, c = e & 63;
        int a = r >> 3, b = r & 7, ca = c >> 3, cb = c & 7;
        float2 h = make_float2(0.f, 0.f);
        if (ca == a + 1 && cb == b - 1) {
            float g = tt * sqrtf((float)((a + 1) * b));
            h.x = g * cp; h.y = g * sp;
        } else if (ca == a - 1 && cb == b + 1) {
            float g = tt * sqrtf((float)(a * (b + 1)));
            h.x = -g * cp; h.y = g * sp;
        }
        float2 xs = make_float2(h.x * fs, h.y * fs);
        X[e] = xs;
        R[e] = make_float2(((r == c) ? 1.f : 0.f) + xs.x * 0.1f, xs.y * 0.1f);
    }
    __syncthreads();
    float2 acc[16];
    for (int j = 9; j >= 1; j--) {
        int q = 0;
        for (int e = t; e < 4096; e += 256, q++) {
            int r = e >> 6, c = e & 63;
            float2 a2 = make_float2(0.f, 0.f);
            for (int k = 0; k < 64; k++) cmac(a2, X[r * 64 + k], R[k * 64 + c]);
            acc[q] = a2;
        }
        __syncthreads();
        float inv = 1.f / (float)j;
        q = 0;
        for (int e = t; e < 4096; e += 256, q++) {
            int r = e >> 6, c = e & 63;
            R[e] = make_float2(((r == c) ? 1.f : 0.f) + acc[q].x * inv, acc[q].y * inv);
        }
        __syncthreads();
    }
    for (int sq = 0; sq < s; sq++) {
        int q = 0;
        for (int e = t; e < 4096; e += 256, q++) {
            int r = e >> 6, c = e & 63;
            float2 a2 = make_float2(0.f, 0.f);
            for (int k = 0; k < 64; k++) cmac(a2, R[r * 64 + k], R[k * 64 + c]);
            acc[q] = a2;
        }
        __syncthreads();
        q = 0;
        for (int e = t; e < 4096; e += 256, q++) R[e] = acc[q];
        __syncthreads();
    }
    for (int e = t; e < 512; e += 256) {
        int o = e >> 3, j = e & 7;
        int n = (o >> 3) + (o & 7);
        int amin = max(0, n - 7);
        int cnt = min(n + 1, 15 - n);
        float2 v = make_float2(0.f, 0.f);
        if (j < cnt) {
            int ka = amin + j, kb = n - ka;
            int k = ka * 8 + kb;
            float ang = php * (float)(o & 7) + pre_i * (float)ka + pre_j * (float)kb;
            float sn, cs; __sincosf(ang, &sn, &cs);
            v = cmul(make_float2(cs, sn), R[o * 64 + k]);
        }
        bsG[blk * 512 + o * 8 + j] = v;
    }
}

// ---------------------------------------------------------------------------
// Main simulation kernel. 1 block (256 thr)/sample. State ping-pongs between
// S[0..4095] (half 0) and S[4096..8191] (half 1) across BS gates.
// ---------------------------------------------------------------------------

// Sparse two-mode gate, template-recursive; reads half PAR, writes half 1-PAR.
template<int M1, int M2, int WQ, int PAR, int NN, int KA>
__device__ __forceinline__ void bs_step(
    Acc16& acc, const float2* S, const float2* __restrict__ Gt, int pb) {
    constexpr int st1 = 512 >> (3 * M1);
    constexpr int st2 = 512 >> (3 * M2);
    constexpr int n = 2 * WQ + NN;
    constexpr int amin = (n > 7) ? (n - 7) : 0;
    constexpr int kamax = (n < 7) ? n : 7;
    if constexpr (KA >= amin && KA <= kamax) {
        constexpr int kb = n - KA;
        constexpr int pk = physw(KA * st1 + kb * st2);
        float2 sv = S[(pb ^ pk) + PAR * 4096];
        if constexpr (NN <= 7) {               // b1 = NN -> acc[NN]
            float2 g = Gt[(16 * WQ + NN) * 8 + (KA - amin)];
            cmac(acc.get<NN>(), g, sv);
        }
        if constexpr (NN >= 1) {               // b2 = NN-1 -> acc[8+NN-1]
            float2 g = Gt[(16 * WQ + 8 + (NN - 1)) * 8 + (KA - amin)];
            cmac(acc.get<8 + NN - 1>(), g, sv);
        }
    }
    if constexpr (KA < 7) bs_step<M1, M2, WQ, PAR, NN, KA + 1>(acc, S, Gt, pb);
    else if constexpr (NN < 8) bs_step<M1, M2, WQ, PAR, NN + 1, 0>(acc, S, Gt, pb);
}

template<int M1, int M2, int WQ, int PAR, int J>
__device__ __forceinline__ void bs_wb(Acc16& acc, float2* S, int pb) {
    constexpr int st1 = 512 >> (3 * M1);
    constexpr int st2 = 512 >> (3 * M2);
    constexpr int a = 2 * WQ + (J >> 3), b = J & 7;
    constexpr int po = physw(a * st1 + b * st2);
    S[(pb ^ po) + (1 - PAR) * 4096] = acc.get<J>();
    if constexpr (J < 15) bs_wb<M1, M2, WQ, PAR, J + 1>(acc, S, pb);
}

template<int M1, int M2, int WQ, int PAR>
__device__ __forceinline__ void bs_gate(
    float2* S, const float2* __restrict__ Gt, int lane) {
    constexpr int freeA = (M1 != 0 && M2 != 0) ? 0 : ((M1 != 1 && M2 != 1) ? 1 : 2);
    constexpr int freeB = (M1 != 3 && M2 != 3) ? 3 : ((M1 != 2 && M2 != 2) ? 2 : 1);
    constexpr int sa = 512 >> (3 * freeA);
    constexpr int sb = 512 >> (3 * freeB);
    int fbase = (lane >> 3) * sa + (lane & 7) * sb;
    int pb = physw(fbase);
    Acc16 acc;
    acc.zero();
    bs_step<M1, M2, WQ, PAR, 0, 0>(acc, S, Gt, pb);
    // No pre-write barrier: writes target the other half, which no wave
    // is reading during this gate.
    bs_wb<M1, M2, WQ, PAR, 0>(acc, S, pb);
    __syncthreads();
}

template<int M1, int M2, int PAR>
__device__ __forceinline__ void do_bs(float2* S, const float2* __restrict__ Gt,
                                      int lane, int wq) {
    switch (wq) {
        case 0: bs_gate<M1, M2, 0, PAR>(S, Gt, lane); break;
        case 1: bs_gate<M1, M2, 1, PAR>(S, Gt, lane); break;
        case 2: bs_gate<M1, M2, 2, PAR>(S, Gt, lane); break;
        default: bs_gate<M1, M2, 3, PAR>(S, Gt, lane); break;
    }
}

// Single-mode 8x8 dense gate on half 0; thread owns 2 private fibers.
template<int MODE, int K, int I>
__device__ __forceinline__ void og_i(Acc16& acc, float2 s0, float2 s1,
                                     const float2* __restrict__ Ut) {
    float2 g = Ut[K * 8 + I];
    cmac(acc.get<I>(), g, s0);
    cmac(acc.get<8 + I>(), g, s1);
    if constexpr (I < 7) og_i<MODE, K, I + 1>(acc, s0, s1, Ut);
}

template<int MODE, int K>
__device__ __forceinline__ void og_k(Acc16& acc, const float2* S,
                                     const float2* __restrict__ Ut,
                                     int pb0, int pb1) {
    constexpr int st = 512 >> (3 * MODE);
    constexpr int pk = physw(K * st);
    float2 s0 = S[pb0 ^ pk];
    float2 s1 = S[pb1 ^ pk];
    og_i<MODE, K, 0>(acc, s0, s1, Ut);
    if constexpr (K < 7) og_k<MODE, K + 1>(acc, S, Ut, pb0, pb1);
}

template<int MODE, int I>
__device__ __forceinline__ void og_wb(Acc16& acc, float2* S, int pb0, int pb1) {
    constexpr int st = 512 >> (3 * MODE);
    constexpr int pi = physw(I * st);
    S[pb0 ^ pi] = acc.get<I>();
    S[pb1 ^ pi] = acc.get<8 + I>();
    if constexpr (I < 7) og_wb<MODE, I + 1>(acc, S, pb0, pb1);
}

template<int MODE>
__device__ __forceinline__ void one_gate(
    float2* S, const float2* __restrict__ Ut, int t) {
    constexpr int F0 = (MODE == 0) ? 64 : 512;
    constexpr int F1 = (MODE <= 1) ? 8 : 64;
    constexpr int F2 = (MODE == 3) ? 8 : 1;
    int f0 = t, f1 = t + 256;
    int fb0 = ((f0 >> 6) & 7) * F0 + ((f0 >> 3) & 7) * F1 + (f0 & 7) * F2;
    int fb1 = ((f1 >> 6) & 7) * F0 + ((f1 >> 3) & 7) * F1 + (f1 & 7) * F2;
    int pb0 = physw(fb0), pb1 = physw(fb1);
    Acc16 acc;
    acc.zero();
    og_k<MODE, 0>(acc, S, Ut, pb0, pb1);
    og_wb<MODE, 0>(acc, S, pb0, pb1);
    __syncthreads();
}

__global__ __launch_bounds__(256, 2) void sim_kernel(
    const float* __restrict__ coh, const float2* __restrict__ sqm,
    const float2* __restrict__ dpm, const float2* __restrict__ bsG,
    float* __restrict__ out) {
    __shared__ float2 S[2 * AMPS];   // 65,536 B -> 2 blocks/CU
    int b = blockIdx.x;
    int t = threadIdx.x;
    int lane = t & 63;
    int wq = __builtin_amdgcn_readfirstlane(t >> 6);

    // Init half 0. For e = t + 256k: i0=k>>1, i1=(t>>6)+4(k&1),
    // i2=(t>>3)&7, i3=t&7.
    {
        const float* cb = coh + b * 32;
        float c23 = cb[16 + ((t >> 3) & 7)] * cb[24 + (t & 7)];
        float c1a = cb[8 + (t >> 6)];
        float c1b = cb[8 + (t >> 6) + 4];
        #pragma unroll
        for (int k = 0; k < 16; k++) {
            float c0 = cb[k >> 1];
            float v = c0 * ((k & 1) ? c1b : c1a) * c23;
            S[physw(t + 256 * k)] = make_float2(v, 0.f);
        }
    }
    __syncthreads();

    #pragma unroll 1
    for (int l = 0; l < NL; l++) {
        #pragma unroll 1
        for (int h = 0; h < 2; h++) {
            const float2* g = bsG + (size_t)(l * 12 + h * 6) * 512;
            do_bs<0, 1, 0>(S, g + 0 * 512, lane, wq);   // 0 -> 1
            do_bs<0, 2, 1>(S, g + 1 * 512, lane, wq);   // 1 -> 0
            do_bs<0, 3, 0>(S, g + 2 * 512, lane, wq);   // 0 -> 1
            do_bs<1, 2, 1>(S, g + 3 * 512, lane, wq);   // 1 -> 0
            do_bs<1, 3, 0>(S, g + 4 * 512, lane, wq);   // 0 -> 1
            do_bs<2, 3, 1>(S, g + 5 * 512, lane, wq);   // 1 -> 0
            const float2* u = ((h == 0) ? sqm : dpm) + (size_t)(l * 4) * 64;
            one_gate<0>(S, u + 0 * 64, t);               // in place, half 0
            one_gate<1>(S, u + 1 * 64, t);
            one_gate<2>(S, u + 2 * 64, t);
            one_gate<3>(S, u + 3 * 64, t);
        }
    }

    // <n_w> per mode: iterate logical index, read physical slot (half 0).
    float ev0 = 0.f, ev1 = 0.f, ev2 = 0.f, ev3 = 0.f;
    for (int e = t; e < AMPS; e += 256) {
        float2 s = S[physw(e)];
        float pr = s.x * s.x + s.y * s.y;
        ev0 += pr * (float)(e >> 9);
        ev1 += pr * (float)((e >> 6) & 7);
        ev2 += pr * (float)((e >> 3) & 7);
        ev3 += pr * (float)(e & 7);
    }
    #pragma unroll
    for (int off = 32; off > 0; off >>= 1) {
        ev0 += __shfl_down(ev0, off);
        ev1 += __shfl_down(ev1, off);
        ev2 += __shfl_down(ev2, off);
        ev3 += __shfl_down(ev3, off);
    }
    __syncthreads();              // all S reads done; S storage now dead
    float* redf = (float*)S;      // overlay 16-float reduction buffer on S
    if (lane == 0) {
        redf[wq * 4 + 0] = ev0;
        redf[wq * 4 + 1] = ev1;
        redf[wq * 4 + 2] = ev2;
        redf[wq * 4 + 3] = ev3;
    }
    __syncthreads();
    if (t < 4) out[b * 4 + t] = redf[t] + redf[4 + t] + redf[8 + t] + redf[12 + t];
}

extern "C" void kernel_launch(void* const* d_in, const int* in_sizes, int n_in,
                              void* d_out, int out_size, void* d_ws, size_t ws_size,
                              hipStream_t stream) {
    const float* x    = (const float*)d_in[0];
    const float* th1  = (const float*)d_in[1];
    const float* ph1  = (const float*)d_in[2];
    const float* th2  = (const float*)d_in[3];
    const float* ph2  = (const float*)d_in[4];
    const float* dpr  = (const float*)d_in[5];
    const float* dpph = (const float*)d_in[6];
    const float* sqr  = (const float*)d_in[7];
    const float* sqph = (const float*)d_in[8];
    const float* kerr = (const float*)d_in[9];
    float* out = (float*)d_out;

    int Bn = in_sizes[0] / NM;

    char* ws = (char*)d_ws;
    float*  coh = (float*)ws;                          // Bn*32 floats
    size_t coh_bytes = (size_t)Bn * 32 * sizeof(float);
    float2* sqm = (float2*)(ws + coh_bytes);           // 16*64 float2
    float2* dpm = (float2*)(ws + coh_bytes + 16 * 64 * sizeof(float2));
    float2* bsG = (float2*)(ws + coh_bytes + 32 * 64 * sizeof(float2)); // 48*512 float2

    int total = Bn * NM;
    coh_kernel<<<(total + 255) / 256, 256, 0, stream>>>(x, coh, total);
    expm8_kernel<<<32, 64, 0, stream>>>(sqr, sqph, dpr, dpph, kerr, sqm, dpm);
    expm64_kernel<<<48, 256, 0, stream>>>(th1, ph1, th2, ph2, bsG);
    sim_kernel<<<Bn, 256, 0, stream>>>(coh, sqm, dpm, bsG, out);
}